// Round 6
// baseline (644.593 us; speedup 1.0000x reference)
//
#include <hip/hip_runtime.h>
#include <hip/hip_fp16.h>
#include <math.h>

#define BATCH 16
#define CIN   128
#define LIN   8192
#define COUT  128
#define LOUT  16384
#define KEXP  768          // 2 shift-halves * (3 powers * 128 channels)
#define NT    128          // i-tile width
#define NTILES (LIN/NT)    // 64
#define PCOLS 130          // i0-1 .. i0+128 inclusive
#define PCPAD 136          // halfwords per col; 272B stride (17x16B: aligned, 4-dword bank skew)
#define PSZ   (PCOLS*PCPAD)  // one plane: 17680 halfwords = 35360 B
#define NITEMS 4           // persistent: work items per block (1024 tiles / 256 blocks)

typedef _Float16 f16x8 __attribute__((ext_vector_type(8)));
typedef float    f32x4 __attribute__((ext_vector_type(4)));

// ---------------- weight prep: fold taps, cast fp16, PHASE-MAJOR frag swizzle ----------------
__global__ void prep_weights(const float* __restrict__ W,
                             _Float16* __restrict__ WE,
                             _Float16* __restrict__ WO) {
  int idx = blockIdx.x * 256 + threadIdx.x;       // 128*768 total
  int co = idx / KEXP;
  int k  = idx % KEXP;
  int sh = (k >= 384) ? 1 : 0;
  int cq = k - 384 * sh;                          // 384 is NOT a power of two
  const float* w = W + ((size_t)co * 384 + cq) * 3;
  float we, wo;
  if (sh == 0) { we = w[0];        wo = w[0] + w[1]; }
  else         { we = w[1] + w[2]; wo = w[2];        }
  int q  = cq >> 7;            // power plane 0..2
  int c  = cq & 127;           // channel within plane
  int ks = q * 8 + sh * 4 + (c >> 5);
  int kk = c & 31, quad = kk >> 3, j = kk & 7;
  int mtile = co >> 4, l15 = co & 15;
  size_t off = ((size_t)((mtile * 24 + ks) * 64) + quad * 16 + l15) * 8 + j;
  WE[off] = (_Float16)we;
  WO[off] = (_Float16)wo;
}

// ---------------- fused conv GEMM ----------------
// v7: PERSISTENT blocks. 256 blocks x 4 items, NT=128, 8 waves (2m x 2n x E/O).
//  - af ring (dist-2) never drains across items (weights identical per item)
//  - next item's x gathered to regs at q1-s4 (~1000cy ahead), LDS-written at q2-s4
//    into the dead buffer -> zero exposed prologue in steady state
//  - P2=P1^2, P3=P2*P1 built in-LDS (owner-computes), buffers alternate per item
//  - 3 barriers/item; stats via direct global atomics (no LDS stage)
//  - F16OUT: pre-norm tensor stored fp16 to workspace (halves norm read traffic)

#define AFLOAD(DST, KS) do {                                               \
  _Pragma("unroll")                                                        \
  for (int fm = 0; fm < 4; ++fm) {                                         \
    int mt = wm * 4 + fm;                                                  \
    DST[fm] = *(const f16x8*)(Wsel + ((size_t)((mt * 24 + (KS)) * 64) + lane) * 8); \
  }                                                                        \
} while (0)

#define BFLOAD(DST, P, S) do {                                             \
  const _Float16* pb = (P) + (((S) & 3) * 32) + kl;                        \
  const int shft = (((S) >> 2) + isO);                                     \
  _Pragma("unroll")                                                        \
  for (int fn = 0; fn < 4; ++fn) {                                         \
    int colB = wn * 64 + fn * 16 + l15 + shft;                             \
    DST[fn] = *(const f16x8*)(pb + colB * PCPAD);                          \
  }                                                                        \
} while (0)

// owner-computes derived planes (each thread r/w only its own cells)
#define BUILD_SQ(SRC, DST) do {                                            \
  _Pragma("unroll")                                                        \
  for (int slot = 0; slot < 5; ++slot) {                                   \
    if (slot < 4 || tail) {                                                \
      f16x8 v = *(f16x8*)((SRC) + woffv[slot]);                            \
      *(f16x8*)((DST) + woffv[slot]) = v * v;                              \
    }                                                                      \
  }                                                                        \
} while (0)

#define BUILD_CU(P1P, P2P) do {                                            \
  _Pragma("unroll")                                                        \
  for (int slot = 0; slot < 5; ++slot) {                                   \
    if (slot < 4 || tail) {                                                \
      f16x8 v1 = *(f16x8*)((P1P) + woffv[slot]);                           \
      f16x8 v2 = *(f16x8*)((P2P) + woffv[slot]);                           \
      *(f16x8*)((P1P) + woffv[slot]) = v1 * v2;                            \
    }                                                                      \
  }                                                                        \
} while (0)

#define XGATHER(WI) do {                                                   \
  const float* xbn = x + (size_t)((WI) >> 6) * CIN * LIN;                  \
  const int i0n = ((WI) & 63) * NT;                                        \
  _Pragma("unroll")                                                        \
  for (int slot = 0; slot < 5; ++slot) {                                   \
    const bool tval = (slot < 4) || tail;                                  \
    int gi = i0n - 1 + colv[slot];                                         \
    const bool ok = tval && gi >= 0 && gi < LIN;                           \
    const float* px = xbn + (size_t)gv[slot] * 8 * LIN + gi;               \
    _Pragma("unroll")                                                      \
    for (int j = 0; j < 8; ++j) xn[slot][j] = ok ? px[(size_t)j * LIN] : 0.f; \
  }                                                                        \
} while (0)

#define XWRITE(DST) do {                                                   \
  _Pragma("unroll")                                                        \
  for (int slot = 0; slot < 5; ++slot) {                                   \
    if (slot < 4 || tail) {                                                \
      f16x8 w;                                                             \
      _Pragma("unroll")                                                    \
      for (int j = 0; j < 8; ++j) w[j] = (_Float16)xn[slot][j];            \
      *(f16x8*)((DST) + woffv[slot]) = w;                                  \
    }                                                                      \
  }                                                                        \
} while (0)

template<int F16OUT>
__launch_bounds__(512, 2)
__global__ void conv_gemm(const float* __restrict__ x,
                          const _Float16* __restrict__ WE,
                          const _Float16* __restrict__ WO,
                          float* __restrict__ out,
                          _Float16* __restrict__ out16,
                          float* __restrict__ stats) {
  extern __shared__ char smem[];
  _Float16* planes = (_Float16*)smem;              // [2][PSZ]

  const int bid  = blockIdx.x;        // 0..255 (persistent)
  const int t    = threadIdx.x;
  const int lane = t & 63;
  const int wave = t >> 6;            // 0..7
  const int isO  = wave & 1;          // 0=even outputs, 1=odd outputs
  const int wn   = (wave >> 1) & 1;   // 64-col half of the tile
  const int wm   = wave >> 2;         // 64-cout half
  const int l15  = lane & 15, quad = lane >> 4;
  const int kl   = quad * 8;

  const _Float16* Wsel = isO ? WO : WE;

  // per-thread staging geometry (identical every item)
  const bool tail = (t < PCOLS * 16 - 2048);       // 2080 tasks; 32 threads own slot 4
  int colv[5], gv[5], woffv[5];
#pragma unroll
  for (int slot = 0; slot < 5; ++slot) {
    int task = t + 512 * slot;
    int g    = task / PCOLS;
    int col  = task - g * PCOLS;
    colv[slot]  = col;
    gv[slot]    = g;
    woffv[slot] = col * PCPAD + g * 8;
  }

  float xn[5][8];
  f32x4 acc[4][4];
  const f32x4 zero = {0.f, 0.f, 0.f, 0.f};
#pragma unroll
  for (int fm = 0; fm < 4; ++fm)
#pragma unroll
    for (int fn = 0; fn < 4; ++fn) acc[fm][fn] = zero;

  f16x8 af[3][4], bf[2][4];
  AFLOAD(af[0], 0);
  AFLOAD(af[1], 1);

  // ---- item 0 prologue: gather + write P1 into buf0 ----
  XGATHER(bid);
  XWRITE(planes);
  __syncthreads();
  BFLOAD(bf[0], planes, 0);

  for (int item = 0; item < NITEMS; ++item) {
    _Float16* cur = planes + (size_t)(item & 1) * PSZ;          // P1 -> P3
    _Float16* oth = planes + (size_t)((item & 1) ^ 1) * PSZ;    // P2, then next P1
    const int wiN = bid + 256 * (item + 1);
    const bool more = (item < NITEMS - 1);

#pragma unroll
    for (int q = 0; q < 3; ++q) {
      const _Float16* pq = (q == 1) ? oth : cur;
#pragma unroll
      for (int s = 0; s < 8; ++s) {
        const int ks = q * 8 + s;
        AFLOAD(af[(ks + 2) % 3], (ks + 2) % 24);       // ring wraps into next item
        if (s < 7) BFLOAD(bf[(s + 1) & 1], pq, s + 1);
        if (q == 0 && s == 0) BUILD_SQ(cur, oth);      // oth <- P1^2
        if (q == 1 && s == 0) BUILD_CU(cur, oth);      // cur <- P1*P2
        if (q == 1 && s == 4) { if (more) XGATHER(wiN); }   // HBM covered by ~12 steps
        if (q == 2 && s == 4) { if (more) XWRITE(oth); }    // oth dead during q2
        __builtin_amdgcn_s_setprio(1);
#pragma unroll
        for (int fm = 0; fm < 4; ++fm)
#pragma unroll
          for (int fn = 0; fn < 4; ++fn)
            acc[fm][fn] = __builtin_amdgcn_mfma_f32_16x16x32_f16(af[ks % 3][fm], bf[s & 1][fn], acc[fm][fn], 0, 0, 0);
        __builtin_amdgcn_s_setprio(0);
      }
      __syncthreads();
      if (q == 0)      BFLOAD(bf[0], oth, 0);
      else if (q == 1) BFLOAD(bf[0], cur, 0);
      else if (more)   BFLOAD(bf[0], oth, 0);          // next item's P1
    }

    // ---- epilogue: stats (direct global atomics) + stores; C/D: n=lane&15, m=quad*4+r
    const int wi = bid + 256 * item;
    const int b  = wi >> 6;
    const int i0 = (wi & 63) * NT;
#pragma unroll
    for (int fm = 0; fm < 4; ++fm) {
#pragma unroll
      for (int r = 0; r < 4; ++r) {
        float s1 = 0.f, s2 = 0.f;
#pragma unroll
        for (int fn = 0; fn < 4; ++fn) {
          float v = acc[fm][fn][r];
          s1 += v;
          s2 += v * v;
        }
#pragma unroll
        for (int off = 8; off >= 1; off >>= 1) {
          s1 += __shfl_xor(s1, off, 64);
          s2 += __shfl_xor(s2, off, 64);
        }
        int co = wm * 64 + fm * 16 + quad * 4 + r;
        if (l15 == 0) {
          atomicAdd(&stats[((size_t)b * COUT + co) * 2],     s1);
          atomicAdd(&stats[((size_t)b * COUT + co) * 2 + 1], s2);
        }
        if (F16OUT) {
          _Float16* orow = out16 + ((size_t)b * COUT + co) * LOUT + isO;
#pragma unroll
          for (int fn = 0; fn < 4; ++fn) {
            int n = i0 + wn * 64 + fn * 16 + l15;
            orow[2 * n] = (_Float16)acc[fm][fn][r];
          }
        } else {
          float* orow = out + ((size_t)b * COUT + co) * LOUT + isO;
#pragma unroll
          for (int fn = 0; fn < 4; ++fn) {
            int n = i0 + wn * 64 + fn * 16 + l15;
            orow[2 * n] = acc[fm][fn][r];
          }
        }
        acc[fm][r < 4 ? 0 : 0][0] = acc[fm][0][0];  // no-op; keep structure simple
      }
    }
#pragma unroll
    for (int fm = 0; fm < 4; ++fm)
#pragma unroll
      for (int fn = 0; fn < 4; ++fn) acc[fm][fn] = zero;
  }
}

// ---------------- instance norm + tanh ----------------
__device__ inline float tanh_fast(float z) {
  float e = __expf(2.f * z);
  return 1.f - 2.f * __builtin_amdgcn_rcpf(e + 1.f);  // v_rcp_f32: no fdiv slow-path
}

template<int F16IN>
__global__ void norm_tanh(float* __restrict__ out, const _Float16* __restrict__ in16,
                          const float* __restrict__ stats) {
  int row = blockIdx.x;                         // b*128 + co
  float s1 = stats[2 * row], s2 = stats[2 * row + 1];
  const float invN = 1.f / (float)LOUT;
  float mean = s1 * invN;
  float var  = fmaxf(s2 * invN - mean * mean, 0.f);
  float inv  = rsqrtf(var + 1e-5f);
  float c0   = -mean * inv;
  if (F16IN) {
    const f16x8* prow = (const f16x8*)(in16 + (size_t)row * LOUT);
    f32x4* orow = (f32x4*)(out + (size_t)row * LOUT);
#pragma unroll
    for (int u = 0; u < 8; ++u) {
      int c = threadIdx.x + 256 * u;
      f16x8 h = prow[c];
      f32x4 a, bq;
      a[0] = tanh_fast(fmaf((float)h[0], inv, c0));
      a[1] = tanh_fast(fmaf((float)h[1], inv, c0));
      a[2] = tanh_fast(fmaf((float)h[2], inv, c0));
      a[3] = tanh_fast(fmaf((float)h[3], inv, c0));
      bq[0] = tanh_fast(fmaf((float)h[4], inv, c0));
      bq[1] = tanh_fast(fmaf((float)h[5], inv, c0));
      bq[2] = tanh_fast(fmaf((float)h[6], inv, c0));
      bq[3] = tanh_fast(fmaf((float)h[7], inv, c0));
      orow[2 * c]     = a;
      orow[2 * c + 1] = bq;
    }
  } else {
    float4* p = (float4*)(out + (size_t)row * LOUT);
#pragma unroll
    for (int mi = 0; mi < 4; ++mi) {
      float4 v[4];
#pragma unroll
      for (int u = 0; u < 4; ++u) v[u] = p[threadIdx.x + 256 * (mi * 4 + u)];
#pragma unroll
      for (int u = 0; u < 4; ++u) {
        v[u].x = tanh_fast(fmaf(v[u].x, inv, c0));
        v[u].y = tanh_fast(fmaf(v[u].y, inv, c0));
        v[u].z = tanh_fast(fmaf(v[u].z, inv, c0));
        v[u].w = tanh_fast(fmaf(v[u].w, inv, c0));
      }
#pragma unroll
      for (int u = 0; u < 4; ++u) p[threadIdx.x + 256 * (mi * 4 + u)] = v[u];
    }
  }
}

extern "C" void kernel_launch(void* const* d_in, const int* in_sizes, int n_in,
                              void* d_out, int out_size, void* d_ws, size_t ws_size,
                              hipStream_t stream) {
  const float* x = (const float*)d_in[0];
  const float* W = (const float*)d_in[1];
  // bias (d_in[2]) is exactly cancelled by InstanceNorm -> unused
  float* out = (float*)d_out;

  float*    stats = (float*)d_ws;
  _Float16* WE    = (_Float16*)((char*)d_ws + 16384);
  _Float16* WO    = WE + (size_t)COUT * KEXP;
  _Float16* O16   = (_Float16*)((char*)d_ws + 409600);
  const size_t need16 = 409600 + (size_t)BATCH * COUT * LOUT * sizeof(_Float16);
  const bool f16path = ws_size >= need16;

  hipMemsetAsync(d_ws, 0, 16384, stream);
  prep_weights<<<dim3((COUT * KEXP) / 256), dim3(256), 0, stream>>>(W, WE, WO);

  size_t shmem = (size_t)PSZ * 2 * 2;   // 70,720 B (2 planes)
  if (f16path) {
    hipFuncSetAttribute(reinterpret_cast<const void*>(&conv_gemm<1>),
                        hipFuncAttributeMaxDynamicSharedMemorySize, (int)shmem);
    conv_gemm<1><<<dim3(256), dim3(512), shmem, stream>>>(x, WE, WO, out, O16, stats);
    norm_tanh<1><<<dim3(BATCH * COUT), dim3(256), 0, stream>>>(out, O16, stats);
  } else {
    hipFuncSetAttribute(reinterpret_cast<const void*>(&conv_gemm<0>),
                        hipFuncAttributeMaxDynamicSharedMemorySize, (int)shmem);
    conv_gemm<0><<<dim3(256), dim3(512), shmem, stream>>>(x, WE, WO, out, O16, stats);
    norm_tanh<0><<<dim3(BATCH * COUT), dim3(256), 0, stream>>>(out, O16, stats);
  }
}